// Round 1
// baseline (159.401 us; speedup 1.0000x reference)
//
#include <hip/hip_runtime.h>
#include <stdint.h>

#define T_SEQ 2048
#define CIN 256
#define COUT 512
#define NHEAD 8
#define DH 64

typedef __bf16 bf16x8 __attribute__((ext_vector_type(8)));
typedef float f32x4 __attribute__((ext_vector_type(4)));
typedef unsigned short u16x8 __attribute__((ext_vector_type(8)));

static __device__ __forceinline__ unsigned short bf16_rne(float f) {
  unsigned u = __builtin_bit_cast(unsigned, f);
  u += 0x7FFFu + ((u >> 16) & 1u);
  return (unsigned short)(u >> 16);
}

static __device__ __forceinline__ bf16x8 ld_frag(const unsigned short* p) {
  u16x8 v = *(const u16x8*)p;
  return __builtin_bit_cast(bf16x8, v);
}

// ---------------- pack: weights f32 -> bf16 ----------------
__global__ __launch_bounds__(256) void pack_w_k(const float* __restrict__ wq,
                                                const float* __restrict__ wk,
                                                const float* __restrict__ wv,
                                                unsigned short* __restrict__ wb) {
  int i = blockIdx.x * 256 + threadIdx.x;            // 3*131072 total
  const float* src = (i < 131072) ? wq : (i < 262144) ? wk : wv;
  wb[i] = bf16_rne(src[i & 131071]);
}

// ---------------- pack: x (n,c,t) f32 -> xT (n,t,c) bf16 ----------------
__global__ __launch_bounds__(256) void pack_xT_k(const float* __restrict__ x,
                                                 unsigned short* __restrict__ xT) {
  __shared__ float tile[64][65];
  const int n = blockIdx.z, c0 = blockIdx.y * 64, t0 = blockIdx.x * 64;
  const int i = threadIdx.x;
  {
    const int cc = i >> 2, tch = (i & 3) * 16;
    const float* src = x + ((size_t)n * CIN + c0 + cc) * T_SEQ + t0 + tch;
    const float4* s4 = (const float4*)src;
#pragma unroll
    for (int q = 0; q < 4; ++q) {
      float4 v = s4[q];
      tile[cc][tch + q * 4 + 0] = v.x;
      tile[cc][tch + q * 4 + 1] = v.y;
      tile[cc][tch + q * 4 + 2] = v.z;
      tile[cc][tch + q * 4 + 3] = v.w;
    }
  }
  __syncthreads();
  {
    const int tt = i >> 2, cch = (i & 3) * 16;
    unsigned short* dst = xT + ((size_t)n * T_SEQ + t0 + tt) * CIN + c0 + cch;
    u16x8 w0, w1;
#pragma unroll
    for (int j = 0; j < 8; ++j) w0[j] = bf16_rne(tile[cch + j][tt]);
#pragma unroll
    for (int j = 0; j < 8; ++j) w1[j] = bf16_rne(tile[cch + 8 + j][tt]);
    *(u16x8*)dst = w0;
    *(u16x8*)(dst + 8) = w1;
  }
}

// ---------------- projection: Yt[t][o] = sum_c xT[t][c] * W[o][c] ----------------
// grid (8 o-tiles, 16 t-tiles, 12 = n*3+w), block 256 (4 waves, 32 t each)
__global__ __launch_bounds__(256) void proj_k(const unsigned short* __restrict__ wb,
                                              const unsigned short* __restrict__ xT,
                                              unsigned short* __restrict__ qb,
                                              unsigned short* __restrict__ kb,
                                              unsigned short* __restrict__ vb) {
  const int z = blockIdx.z;
  const int n = z / 3, w = z % 3;
  const unsigned short* W = wb + (size_t)w * COUT * CIN;
  const unsigned short* X = xT + (size_t)n * T_SEQ * CIN;
  const int tid = threadIdx.x, wave = tid >> 6, lane = tid & 63;
  const int c = lane & 15, g = lane >> 4;
  const int o0 = blockIdx.x * 64;
  const int t0 = blockIdx.y * 128 + wave * 32;

  f32x4 acc[2][4];
  const f32x4 z4 = {0.f, 0.f, 0.f, 0.f};
#pragma unroll
  for (int mt = 0; mt < 2; ++mt)
#pragma unroll
    for (int no = 0; no < 4; ++no) acc[mt][no] = z4;

  for (int c0 = 0; c0 < CIN; c0 += 32) {
    bf16x8 a[2], b[4];
#pragma unroll
    for (int mt = 0; mt < 2; ++mt)
      a[mt] = ld_frag(X + (size_t)(t0 + mt * 16 + c) * CIN + c0 + g * 8);
#pragma unroll
    for (int no = 0; no < 4; ++no)
      b[no] = ld_frag(W + (size_t)(o0 + no * 16 + c) * CIN + c0 + g * 8);
#pragma unroll
    for (int mt = 0; mt < 2; ++mt)
#pragma unroll
      for (int no = 0; no < 4; ++no)
        acc[mt][no] = __builtin_amdgcn_mfma_f32_16x16x32_bf16(a[mt], b[no], acc[mt][no], 0, 0, 0);
  }

  unsigned short* dst = (w == 0) ? qb : (w == 1) ? kb : vb;
  const float scale = (w == 0) ? 0.125f : 1.0f;  // fold 1/sqrt(dk) into q
  const int h = o0 >> 6;
  const size_t base = ((size_t)(n * NHEAD + h)) * T_SEQ * DH;
#pragma unroll
  for (int mt = 0; mt < 2; ++mt)
#pragma unroll
    for (int no = 0; no < 4; ++no)
#pragma unroll
      for (int r = 0; r < 4; ++r) {
        const int t = t0 + mt * 16 + 4 * g + r;
        const int d = no * 16 + c;
        dst[base + (size_t)t * DH + d] = bf16_rne(acc[mt][no][r] * scale);
      }
}

// ---------------- flash attention ----------------
// grid (16 tq-tiles, 32 nh), block 256 (4 waves x 32 tq). BK=64.
// q,k,v: bf16 t-major [nh][t][64]. out: f32 (n,512,2048).
__global__ __launch_bounds__(256) void attn_k(const unsigned short* __restrict__ qb,
                                              const unsigned short* __restrict__ kb,
                                              const unsigned short* __restrict__ vb,
                                              float* __restrict__ outp) {
  __shared__ unsigned short Vt[64 * 64];   // row d (64 elems/row), swizzled e^=(d&7)<<3
  __shared__ unsigned short Pl[128 * 64];  // row tq-local (64 elems/row), per-wave slice
  const int nh = blockIdx.y;
  const int tid = threadIdx.x;
  const int wave = tid >> 6, lane = tid & 63;
  const int c = lane & 15, g = lane >> 4;
  const int tq0 = blockIdx.x * 128 + wave * 32;
  const unsigned short* Q = qb + (size_t)nh * T_SEQ * DH;
  const unsigned short* K = kb + (size_t)nh * T_SEQ * DH;
  const unsigned short* V = vb + (size_t)nh * T_SEQ * DH;

  bf16x8 qf[2][2];
#pragma unroll
  for (int nq = 0; nq < 2; ++nq)
#pragma unroll
    for (int kk = 0; kk < 2; ++kk)
      qf[nq][kk] = ld_frag(Q + (size_t)(tq0 + nq * 16 + c) * DH + kk * 32 + g * 8);

  f32x4 oacc[2][4];
  const f32x4 z4 = {0.f, 0.f, 0.f, 0.f};
#pragma unroll
  for (int nq = 0; nq < 2; ++nq)
#pragma unroll
    for (int nd = 0; nd < 4; ++nd) oacc[nq][nd] = z4;
  float m_run[2] = {-3.0e38f, -3.0e38f};
  float l_run[2] = {0.f, 0.f};

  const int chunk = tid & 7;   // d-chunk for V staging
  const int tkp = tid >> 3;    // 0..31 -> rows 2*tkp, 2*tkp+1

  for (int tk0 = 0; tk0 < T_SEQ; tk0 += 64) {
    __syncthreads();  // Vt from previous iter fully consumed
    {   // stage V[tk0..+63][0..63] -> Vt[d][tk] (transposed, swizzled)
      const unsigned short* src = V + (size_t)(tk0 + 2 * tkp) * DH + chunk * 8;
      u16x8 r0 = *(const u16x8*)src;
      u16x8 r1 = *(const u16x8*)(src + DH);
#pragma unroll
      for (int jj = 0; jj < 8; ++jj) {
        const int d = chunk * 8 + jj;
        const unsigned pw = (unsigned)r0[jj] | ((unsigned)r1[jj] << 16);
        const int e = (d * 64 + 2 * tkp) ^ ((d & 7) << 3);
        *(unsigned*)&Vt[e] = pw;
      }
    }
    // S = K^T-tile x Q-tile (overlaps with V staging; no Vt dependency)
    f32x4 s[4][2];
#pragma unroll
    for (int m16 = 0; m16 < 4; ++m16) {
      const unsigned short* kr = K + (size_t)(tk0 + m16 * 16 + c) * DH;
      bf16x8 kf0 = ld_frag(kr + g * 8);
      bf16x8 kf1 = ld_frag(kr + 32 + g * 8);
#pragma unroll
      for (int nq = 0; nq < 2; ++nq) {
        f32x4 t = z4;
        t = __builtin_amdgcn_mfma_f32_16x16x32_bf16(kf0, qf[nq][0], t, 0, 0, 0);
        t = __builtin_amdgcn_mfma_f32_16x16x32_bf16(kf1, qf[nq][1], t, 0, 0, 0);
        s[m16][nq] = t;
      }
    }
    __syncthreads();  // Vt ready
    // hoist V fragments for both nq
    bf16x8 vf[4][2];
#pragma unroll
    for (int nd = 0; nd < 4; ++nd)
#pragma unroll
      for (int kk = 0; kk < 2; ++kk) {
        const int row = nd * 16 + c;
        const int e = (row * 64 + kk * 32 + g * 8) ^ ((row & 7) << 3);
        vf[nd][kk] = ld_frag(&Vt[e]);
      }
    // online softmax per tq column (lane owns column c of its nq block)
#pragma unroll
    for (int nq = 0; nq < 2; ++nq) {
      float pm = s[0][nq][0];
#pragma unroll
      for (int m16 = 0; m16 < 4; ++m16)
#pragma unroll
        for (int r = 0; r < 4; ++r) pm = fmaxf(pm, s[m16][nq][r]);
      pm = fmaxf(pm, __shfl_xor(pm, 16));
      pm = fmaxf(pm, __shfl_xor(pm, 32));
      const float mnew = fmaxf(m_run[nq], pm);
      const float alpha = __expf(m_run[nq] - mnew);
      m_run[nq] = mnew;
      float colsum = 0.f;
      const int prow = wave * 32 + nq * 16 + c;
#pragma unroll
      for (int m16 = 0; m16 < 4; ++m16) {
        unsigned short pb[4];
#pragma unroll
        for (int r = 0; r < 4; ++r) {
          const float p = __expf(s[m16][nq][r] - mnew);
          colsum += p;
          pb[r] = bf16_rne(p);
        }
#pragma unroll
        for (int pr = 0; pr < 2; ++pr) {
          const unsigned pw = (unsigned)pb[2 * pr] | ((unsigned)pb[2 * pr + 1] << 16);
          const int tk = m16 * 16 + 4 * g + 2 * pr;
          const int e = (prow * 64 + tk) ^ ((prow & 7) << 3);
          *(unsigned*)&Pl[e] = pw;
        }
      }
      colsum += __shfl_xor(colsum, 16);
      colsum += __shfl_xor(colsum, 32);
      l_run[nq] = l_run[nq] * alpha + colsum;
      float ar[4];
#pragma unroll
      for (int r = 0; r < 4; ++r) ar[r] = __shfl(alpha, 4 * g + r);
#pragma unroll
      for (int nd = 0; nd < 4; ++nd)
#pragma unroll
        for (int r = 0; r < 4; ++r) oacc[nq][nd][r] *= ar[r];
    }
    // PV: O[tq][d] += P^T x V  (A = Pl rows, B = Vt rows)
#pragma unroll
    for (int nq = 0; nq < 2; ++nq) {
      const int prow = wave * 32 + nq * 16 + c;
      bf16x8 pa0 = ld_frag(&Pl[(prow * 64 + 0 * 32 + g * 8) ^ ((prow & 7) << 3)]);
      bf16x8 pa1 = ld_frag(&Pl[(prow * 64 + 1 * 32 + g * 8) ^ ((prow & 7) << 3)]);
#pragma unroll
      for (int nd = 0; nd < 4; ++nd) {
        oacc[nq][nd] = __builtin_amdgcn_mfma_f32_16x16x32_bf16(pa0, vf[nd][0], oacc[nq][nd], 0, 0, 0);
        oacc[nq][nd] = __builtin_amdgcn_mfma_f32_16x16x32_bf16(pa1, vf[nd][1], oacc[nq][nd], 0, 0, 0);
      }
    }
  }

  // epilogue: normalize and store f32 out[n][h*64+d][t]
  const int n = nh >> 3, h = nh & 7;
  const size_t obase = (size_t)(n * COUT + h * DH) * T_SEQ;
#pragma unroll
  for (int nq = 0; nq < 2; ++nq) {
    float invl[4];
#pragma unroll
    for (int r = 0; r < 4; ++r) invl[r] = 1.0f / __shfl(l_run[nq], 4 * g + r);
#pragma unroll
    for (int nd = 0; nd < 4; ++nd)
#pragma unroll
      for (int r = 0; r < 4; ++r) {
        const int t = tq0 + nq * 16 + 4 * g + r;
        const int d = nd * 16 + c;
        outp[obase + (size_t)d * T_SEQ + t] = oacc[nq][nd][r] * invl[r];
      }
  }
}

extern "C" void kernel_launch(void* const* d_in, const int* in_sizes, int n_in,
                              void* d_out, int out_size, void* d_ws, size_t ws_size,
                              hipStream_t stream) {
  (void)in_sizes; (void)n_in; (void)out_size; (void)ws_size;
  const float* x  = (const float*)d_in[0];
  const float* Wq = (const float*)d_in[1];
  const float* Wk = (const float*)d_in[2];
  const float* Wv = (const float*)d_in[3];
  float* outp = (float*)d_out;

  char* ws = (char*)d_ws;
  unsigned short* wb = (unsigned short*)ws;                         // 786432 B
  unsigned short* xT = (unsigned short*)(ws + 786432);              // 4194304 B
  unsigned short* qb = (unsigned short*)(ws + 786432 + 4194304);    // 8388608 B each
  unsigned short* kb = qb + 4194304;
  unsigned short* vb = kb + 4194304;

  pack_w_k<<<1536, 256, 0, stream>>>(Wq, Wk, Wv, wb);
  pack_xT_k<<<dim3(32, 4, 4), 256, 0, stream>>>(x, xT);
  proj_k<<<dim3(8, 16, 12), 256, 0, stream>>>(wb, xT, qb, kb, vb);
  attn_k<<<dim3(16, 32), 256, 0, stream>>>(qb, kb, vb, outp);
}